// Round 1
// baseline (355.193 us; speedup 1.0000x reference)
//
#include <hip/hip_runtime.h>

// OutputNeuron scan: per-(b,n) element, fully independent recurrence over T.
//   syn = 0.9*syn + x_t ; mem = 0.95*mem + syn ; s = (mem>1) ; count += s ;
//   mem *= (1-s)
// Memory-bound: must stream 268 MB of x. One thread per 4 contiguous elements
// (float4 coalesced loads); state carried in registers; single output write.

#define NEURON_ALPHA 0.9f
#define NEURON_BETA  0.95f

__global__ __launch_bounds__(256) void outneuron_scan_kernel(
    const float* __restrict__ x,
    const float* __restrict__ mem0,
    const float* __restrict__ syn0,
    const float* __restrict__ count0,
    float* __restrict__ out,
    int BN, int T)
{
    const int i4  = blockIdx.x * blockDim.x + threadIdx.x; // float4 column index
    const int idx = i4 << 2;
    if (idx >= BN) return;

    float4 syn = *reinterpret_cast<const float4*>(syn0   + idx);
    float4 mem = *reinterpret_cast<const float4*>(mem0   + idx);
    float4 cnt = *reinterpret_cast<const float4*>(count0 + idx);

    const float4* xp = reinterpret_cast<const float4*>(x) + i4;
    const size_t s4 = (size_t)(BN >> 2); // float4 stride between timesteps

#define NEURON_STEP(c)                                   \
    do {                                                 \
        syn.c = NEURON_ALPHA * syn.c + xt.c;             \
        mem.c = NEURON_BETA  * mem.c + syn.c;            \
        bool sp = (mem.c > 1.0f);                        \
        cnt.c += sp ? 1.0f : 0.0f;                       \
        mem.c  = sp ? 0.0f : mem.c;                      \
    } while (0)

    // Loads at successive t are address-independent; unroll so the compiler
    // keeps ~4 global_load_dwordx4 in flight per wave (latency hiding).
#pragma unroll 4
    for (int t = 0; t < T; ++t) {
        float4 xt = xp[(size_t)t * s4];
        NEURON_STEP(x);
        NEURON_STEP(y);
        NEURON_STEP(z);
        NEURON_STEP(w);
    }
#undef NEURON_STEP

    *reinterpret_cast<float4*>(out + idx) = cnt;
}

extern "C" void kernel_launch(void* const* d_in, const int* in_sizes, int n_in,
                              void* d_out, int out_size, void* d_ws, size_t ws_size,
                              hipStream_t stream) {
    const float* x      = (const float*)d_in[0];
    const float* mem0   = (const float*)d_in[1];
    const float* syn0   = (const float*)d_in[2];
    const float* count0 = (const float*)d_in[3];
    float* out = (float*)d_out;

    const int BN = in_sizes[1];          // B*N = 524288 (divisible by 4)
    const int T  = in_sizes[0] / BN;     // 128

    const int n_threads = BN >> 2;       // one thread per float4
    dim3 block(256);
    dim3 grid((n_threads + block.x - 1) / block.x);
    outneuron_scan_kernel<<<grid, block, 0, stream>>>(x, mem0, syn0, count0, out, BN, T);
}

// Round 3
// 334.739 us; speedup vs baseline: 1.0611x; 1.0611x over previous
//
#include <hip/hip_runtime.h>

// OutputNeuron scan: per-(b,n) element, fully independent recurrence over T.
//   syn = 0.9*syn + x_t ; mem = 0.95*mem + syn ; s = (mem>1) ; count += s ;
//   mem *= (1-s)
// Memory-bound: must stream 268 MB of x once. One thread per float4 column;
// explicit 4-deep rotating prefetch pipeline keeps 3-4 global_load_dwordx4
// outstanding per wave at all times (avoids per-iteration vmcnt(0) drain),
// nontemporal loads since x has zero reuse.
//
// Note: __builtin_nontemporal_load requires a native vector type, not HIP's
// HIP_vector_type struct -> use ext_vector_type(4) float for the x stream.

typedef float vfloat4 __attribute__((ext_vector_type(4)));

#define NEURON_ALPHA 0.9f
#define NEURON_BETA  0.95f

#define NEURON_STEP(c)                                   \
    do {                                                 \
        syn[c] = NEURON_ALPHA * syn[c] + xt[c];          \
        mem[c] = NEURON_BETA  * mem[c] + syn[c];         \
        bool sp = (mem[c] > 1.0f);                       \
        cnt[c] += sp ? 1.0f : 0.0f;                      \
        mem[c]  = sp ? 0.0f : mem[c];                    \
    } while (0)

__global__ __launch_bounds__(256) void outneuron_scan_kernel(
    const float* __restrict__ x,
    const float* __restrict__ mem0,
    const float* __restrict__ syn0,
    const float* __restrict__ count0,
    float* __restrict__ out,
    int BN, int T)
{
    const int i4  = blockIdx.x * blockDim.x + threadIdx.x; // float4 column index
    const int idx = i4 << 2;
    if (idx >= BN) return;

    vfloat4 syn = *reinterpret_cast<const vfloat4*>(syn0   + idx);
    vfloat4 mem = *reinterpret_cast<const vfloat4*>(mem0   + idx);
    vfloat4 cnt = *reinterpret_cast<const vfloat4*>(count0 + idx);

    const vfloat4* xp = reinterpret_cast<const vfloat4*>(x) + i4;
    const size_t s4 = (size_t)(BN >> 2); // vfloat4 stride between timesteps

    // Prologue: fill the 4-deep pipeline (assumes T >= 8; here T = 128).
    vfloat4 buf[4];
#pragma unroll
    for (int k = 0; k < 4; ++k)
        buf[k] = __builtin_nontemporal_load(xp + (size_t)k * s4);
    xp += 4 * s4;

    // Steady state: compute with the load from 4 iterations ago; issue the
    // replacement load immediately. Unroll 4 so buf[] indices are constants
    // (stays in registers) and the wave always has ~4 loads in flight
    // (compiler emits s_waitcnt vmcnt(3), never vmcnt(0), in this loop).
    int i = 0;
#pragma unroll 4
    for (; i < T - 4; ++i) {
        vfloat4 xt = buf[i & 3];
        buf[i & 3] = __builtin_nontemporal_load(xp);
        xp += s4;
        NEURON_STEP(0);
        NEURON_STEP(1);
        NEURON_STEP(2);
        NEURON_STEP(3);
    }

    // Epilogue: drain the last 4 buffered timesteps (no more loads).
    for (; i < T; ++i) {
        vfloat4 xt = buf[i & 3];
        NEURON_STEP(0);
        NEURON_STEP(1);
        NEURON_STEP(2);
        NEURON_STEP(3);
    }

    *reinterpret_cast<vfloat4*>(out + idx) = cnt;
}

extern "C" void kernel_launch(void* const* d_in, const int* in_sizes, int n_in,
                              void* d_out, int out_size, void* d_ws, size_t ws_size,
                              hipStream_t stream) {
    const float* x      = (const float*)d_in[0];
    const float* mem0   = (const float*)d_in[1];
    const float* syn0   = (const float*)d_in[2];
    const float* count0 = (const float*)d_in[3];
    float* out = (float*)d_out;

    const int BN = in_sizes[1];          // B*N = 524288 (divisible by 4)
    const int T  = in_sizes[0] / BN;     // 128

    const int n_threads = BN >> 2;       // one thread per float4
    dim3 block(256);
    dim3 grid((n_threads + block.x - 1) / block.x);
    outneuron_scan_kernel<<<grid, block, 0, stream>>>(x, mem0, syn0, count0, out, BN, T);
}